// Round 1
// baseline (1898.602 us; speedup 1.0000x reference)
//
#include <hip/hip_runtime.h>
#include <math.h>

#define N_NODES 8192
#define N_EDGES 32768
#define HID 8
#define FEAT 11          // HID + 3
#define E4   (N_EDGES/4) // 8192 float4 per matrix row (power of 2)

// Scan a dense one-hot incidence matrix [N_NODES, N_EDGES] (row-major) and
// recover the per-column node index. Exactly one nonzero per column, so the
// plain (non-atomic) store is race-free. Fully coalesced float4 streaming.
__global__ void scan_incidence(const float4* __restrict__ mat,
                               int* __restrict__ idx) {
    const long total4 = (long)N_NODES * E4;  // 2^26
    const long stride = (long)gridDim.x * blockDim.x;
    for (long j = (long)blockIdx.x * blockDim.x + threadIdx.x;
         j < total4; j += stride) {
        float4 v = mat[j];
        int n = (int)(j >> 13);            // row  = j / E4   (E4 = 2^13)
        int e = (((int)j) & (E4 - 1)) << 2; // col  = (j % E4) * 4
        if (v.x != 0.0f) idx[e + 0] = n;
        if (v.y != 0.0f) idx[e + 1] = n;
        if (v.z != 0.0f) idx[e + 2] = n;
        if (v.w != 0.0f) idx[e + 3] = n;
    }
}

// Per-edge: gather both endpoint feature rows, run the 2-layer MLP.
// B = [X[idx_o[e]], X[idx_i[e]]] (bo first, bi second, matching the
// reference's concatenate([bo, bi])), h = tanh(B @ W1 + b1),
// out = sigmoid(h @ W2 + b2).
__global__ void edge_mlp(const float* __restrict__ X,
                         const int*   __restrict__ idx_i,
                         const int*   __restrict__ idx_o,
                         const float* __restrict__ W1,  // [2*FEAT, HID]
                         const float* __restrict__ b1,  // [HID]
                         const float* __restrict__ W2,  // [HID]
                         const float* __restrict__ b2,  // [1]
                         float* __restrict__ out) {
    int e = blockIdx.x * blockDim.x + threadIdx.x;
    if (e >= N_EDGES) return;

    const float* xo = X + (long)idx_o[e] * FEAT;
    const float* xi = X + (long)idx_i[e] * FEAT;

    float h[HID];
#pragma unroll
    for (int j = 0; j < HID; ++j) h[j] = b1[j];

#pragma unroll
    for (int f = 0; f < FEAT; ++f) {
        float vo = xo[f];
        float vi = xi[f];
#pragma unroll
        for (int j = 0; j < HID; ++j) {
            h[j] += vo * W1[f * HID + j] + vi * W1[(FEAT + f) * HID + j];
        }
    }

    float acc = b2[0];
#pragma unroll
    for (int j = 0; j < HID; ++j) acc += tanhf(h[j]) * W2[j];

    out[e] = 1.0f / (1.0f + expf(-acc));
}

extern "C" void kernel_launch(void* const* d_in, const int* in_sizes, int n_in,
                              void* d_out, int out_size, void* d_ws, size_t ws_size,
                              hipStream_t stream) {
    const float* X  = (const float*)d_in[0];  // [8192, 11]
    const float* Ri = (const float*)d_in[1];  // [8192, 32768]
    const float* Ro = (const float*)d_in[2];  // [8192, 32768]
    const float* W1 = (const float*)d_in[3];  // [22, 8]
    const float* b1 = (const float*)d_in[4];  // [8]
    const float* W2 = (const float*)d_in[5];  // [8]
    const float* b2 = (const float*)d_in[6];  // [1]
    float* out = (float*)d_out;               // [32768]

    int* idx_i = (int*)d_ws;           // 32768 ints (every slot written by scan)
    int* idx_o = idx_i + N_EDGES;      // 32768 ints

    // 4096 blocks x 256 threads: 64 float4 loads per thread, fully streaming.
    scan_incidence<<<4096, 256, 0, stream>>>((const float4*)Ri, idx_i);
    scan_incidence<<<4096, 256, 0, stream>>>((const float4*)Ro, idx_o);

    edge_mlp<<<(N_EDGES + 255) / 256, 256, 0, stream>>>(
        X, idx_i, idx_o, W1, b1, W2, b2, out);
}